// Round 1
// baseline (2287.710 us; speedup 1.0000x reference)
//
#include <hip/hip_runtime.h>
#include <hip/hip_bf16.h>

// Problem constants
#define BB    128
#define C_IN  9
#define T0    2048
#define T1    1024      // after pool1
#define T2    512       // after pool2
#define NN    65536     // B * T2 nodes
#define EE    524288    // edges
#define FEAT  32
#define HID   128
#define OUTC  6

// ---------------- conv1: [B,9,2048] -> relu -> pool2 -> h1 [B,16,1024] ----------------
__global__ __launch_bounds__(256) void k_conv1(const float* __restrict__ x,
                                               const float* __restrict__ w,
                                               const float* __restrict__ bias,
                                               float* __restrict__ h1) {
    int idx = blockIdx.x * 256 + threadIdx.x;          // over B*16*T1
    if (idx >= BB * 16 * T1) return;
    int tt = idx & (T1 - 1);
    int o  = (idx >> 10) & 15;
    int b  = idx >> 14;
    const float* xb = x + (size_t)b * C_IN * T0;
    const float* wo = w + o * C_IN * 5;
    float a0 = 0.f, a1 = 0.f;
    int t0 = 2 * tt;
    #pragma unroll
    for (int c = 0; c < C_IN; ++c) {
        const float* xc = xb + c * T0;
        #pragma unroll
        for (int k = 0; k < 5; ++k) {
            float wv = wo[c * 5 + k];
            int ta = t0 + k - 2;
            int tb = ta + 1;
            if ((unsigned)ta < T0) a0 += xc[ta] * wv;
            if ((unsigned)tb < T0) a1 += xc[tb] * wv;
        }
    }
    float bi = bias[o];
    a0 = fmaxf(a0 + bi, 0.f);
    a1 = fmaxf(a1 + bi, 0.f);
    h1[idx] = fmaxf(a0, a1);
}

// ---------------- conv2: h1 [B,16,1024] -> relu -> pool2 -> nodes [N,32] ----------------
__global__ __launch_bounds__(256) void k_conv2(const float* __restrict__ h1,
                                               const float* __restrict__ w,
                                               const float* __restrict__ bias,
                                               float* __restrict__ nodes) {
    int idx = blockIdx.x * 256 + threadIdx.x;          // over N*32
    if (idx >= NN * FEAT) return;
    int o    = idx & 31;
    int node = idx >> 5;
    int tt   = node & (T2 - 1);
    int b    = node >> 9;
    const float* hb = h1 + (size_t)b * 16 * T1;
    const float* wo = w + o * 16 * 5;
    float a0 = 0.f, a1 = 0.f;
    int t0 = 2 * tt;
    #pragma unroll
    for (int c = 0; c < 16; ++c) {
        const float* hc = hb + c * T1;
        #pragma unroll
        for (int k = 0; k < 5; ++k) {
            float wv = wo[c * 5 + k];
            int ta = t0 + k - 2;
            int tb = ta + 1;
            if ((unsigned)ta < T1) a0 += hc[ta] * wv;
            if ((unsigned)tb < T1) a1 += hc[tb] * wv;
        }
    }
    float bi = bias[o];
    a0 = fmaxf(a0 + bi, 0.f);
    a1 = fmaxf(a1 + bi, 0.f);
    nodes[idx] = fmaxf(a0, a1);
}

// ---------------- degree count at dst (float atomics: exact for integer counts) --------
__global__ __launch_bounds__(256) void k_deg(const int* __restrict__ ei,
                                             float* __restrict__ deg) {
    int e = blockIdx.x * 256 + threadIdx.x;
    if (e < EE) unsafeAtomicAdd(&deg[ei[EE + e]], 1.0f);
}

__global__ __launch_bounds__(256) void k_dis(float* __restrict__ deg) {
    int n = blockIdx.x * 256 + threadIdx.x;
    if (n < NN) deg[n] = rsqrtf(deg[n] + 1.0f);
}

// ---------------- GCN1 GEMM: xw = nodes @ W1 ; agg = xw * dis^2 ----------------
#define NPB1 16
__global__ __launch_bounds__(256) void k_gemm1(const float* __restrict__ nodes,
                                               const float* __restrict__ w1,
                                               const float* __restrict__ dis,
                                               float* __restrict__ xw,
                                               float* __restrict__ agg) {
    __shared__ float sw[FEAT * HID];       // 16 KiB
    __shared__ float srow[NPB1][FEAT];
    for (int i = threadIdx.x; i < FEAT * HID; i += 256) sw[i] = w1[i];
    int base = blockIdx.x * NPB1;
    for (int i = threadIdx.x; i < NPB1 * FEAT; i += 256)
        srow[i >> 5][i & 31] = nodes[(size_t)base * FEAT + i];
    __syncthreads();
    int o    = threadIdx.x & 127;
    int half = threadIdx.x >> 7;
    for (int j = half; j < NPB1; j += 2) {
        int n = base + j;
        float acc = 0.f;
        #pragma unroll
        for (int k = 0; k < FEAT; ++k) acc += srow[j][k] * sw[k * HID + o];
        float di = dis[n];
        size_t off = (size_t)n * HID + o;
        xw[off]  = acc;
        agg[off] = acc * di * di;
    }
}

// ---------------- edge scatter: agg[dst] += xw[src] * dis[src]*dis[dst] ----------------
__global__ __launch_bounds__(256) void k_scatter(const int* __restrict__ ei,
                                                 const float* __restrict__ xw,
                                                 const float* __restrict__ dis,
                                                 float* __restrict__ agg) {
    int t = blockIdx.x * 256 + threadIdx.x;
    int e = t >> 5;                       // 32 lanes per edge
    if (e >= EE) return;
    int lane = t & 31;
    int s = ei[e];
    int d = ei[EE + e];
    float norm = dis[s] * dis[d];
    float4 v = ((const float4*)(xw + (size_t)s * HID))[lane];
    float* dst = agg + (size_t)d * HID + lane * 4;
    unsafeAtomicAdd(dst + 0, v.x * norm);
    unsafeAtomicAdd(dst + 1, v.y * norm);
    unsafeAtomicAdd(dst + 2, v.z * norm);
    unsafeAtomicAdd(dst + 3, v.w * norm);
}

// ---------------- GCN2 GEMM: g = relu(agg1 + b1); xw2 = g @ W2 ; agg2 = xw2*dis^2 ------
// In-place: aggIn == agg2Out is safe (each row is staged to LDS before overwrite,
// and each row is owned by exactly one block).
#define NPB2 32
__global__ __launch_bounds__(256) void k_gemm2(const float* __restrict__ aggIn,
                                               const float* __restrict__ b1,
                                               const float* __restrict__ w2,
                                               const float* __restrict__ dis,
                                               float* __restrict__ xw2,
                                               float* __restrict__ agg2) {
    __shared__ float sw[HID * HID];        // 64 KiB
    __shared__ float srow[2][HID];
    for (int i = threadIdx.x; i < HID * HID; i += 256) sw[i] = w2[i];
    int o    = threadIdx.x & 127;
    int half = threadIdx.x >> 7;
    int base = blockIdx.x * NPB2;
    float bo = b1[o];
    for (int j = 0; j < NPB2; j += 2) {
        int n = base + j + half;
        __syncthreads();   // protect srow reuse from previous iteration (and sw on first)
        srow[half][o] = fmaxf(aggIn[(size_t)n * HID + o] + bo, 0.f);
        __syncthreads();
        float acc = 0.f;
        #pragma unroll
        for (int k = 0; k < HID; ++k) acc += srow[half][k] * sw[k * HID + o];
        float di = dis[n];
        size_t off = (size_t)n * HID + o;
        xw2[off]  = acc;
        agg2[off] = acc * di * di;
    }
}

// ---------------- finalize: g2 = relu(agg2+b2); mean over T2; @ cls_w + cls_b ----------
__global__ __launch_bounds__(128) void k_final(const float* __restrict__ agg2,
                                               const float* __restrict__ b2,
                                               const float* __restrict__ clsw,
                                               const float* __restrict__ clsb,
                                               float* __restrict__ out) {
    __shared__ float pooled[HID];
    int b = blockIdx.x;
    int f = threadIdx.x;
    float bo = b2[f];
    float sum = 0.f;
    const float* basep = agg2 + (size_t)b * T2 * HID + f;
    for (int tt = 0; tt < T2; ++tt)
        sum += fmaxf(basep[(size_t)tt * HID] + bo, 0.f);
    pooled[f] = sum * (1.0f / (float)T2);
    __syncthreads();
    if (f < OUTC) {
        float acc = clsb[f];
        #pragma unroll 8
        for (int k = 0; k < HID; ++k) acc += pooled[k] * clsw[k * OUTC + f];
        out[b * OUTC + f] = acc;
    }
}

extern "C" void kernel_launch(void* const* d_in, const int* in_sizes, int n_in,
                              void* d_out, int out_size, void* d_ws, size_t ws_size,
                              hipStream_t stream) {
    const float* x    = (const float*)d_in[0];
    const int*   ei   = (const int*)d_in[1];
    const float* c1w  = (const float*)d_in[2];
    const float* c1b  = (const float*)d_in[3];
    const float* c2w  = (const float*)d_in[4];
    const float* c2b  = (const float*)d_in[5];
    const float* g1w  = (const float*)d_in[6];
    const float* g1b  = (const float*)d_in[7];
    const float* g2w  = (const float*)d_in[8];
    const float* g2b  = (const float*)d_in[9];
    const float* clsw = (const float*)d_in[10];
    const float* clsb = (const float*)d_in[11];
    float* out = (float*)d_out;

    float* ws = (float*)d_ws;
    // xw region doubles as h1 scratch (h1 dead before gemm1 runs; stream-ordered)
    float* xw    = ws;                       // 8388608 floats (h1 = first 2097152)
    float* h1    = ws;
    float* agg   = ws + 8388608;             // 8388608 floats
    float* nodes = ws + 16777216;            // 2097152 floats
    float* dis   = ws + 18874368;            // 65536 floats
    // total 18939904 floats = 75.8 MB

    hipMemsetAsync(dis, 0, NN * sizeof(float), stream);

    k_conv1<<<(BB * 16 * T1) / 256, 256, 0, stream>>>(x, c1w, c1b, h1);
    k_conv2<<<(NN * FEAT) / 256, 256, 0, stream>>>(h1, c2w, c2b, nodes);
    k_deg<<<(EE + 255) / 256, 256, 0, stream>>>(ei, dis);
    k_dis<<<(NN + 255) / 256, 256, 0, stream>>>(dis);

    // GCN layer 1
    k_gemm1<<<NN / NPB1, 256, 0, stream>>>(nodes, g1w, dis, xw, agg);
    k_scatter<<<(EE * 32) / 256, 256, 0, stream>>>(ei, xw, dis, agg);

    // GCN layer 2 (relu+bias fused into A-row load; agg in-place)
    k_gemm2<<<NN / NPB2, 256, 0, stream>>>(agg, g1b, g2w, dis, xw, agg);
    k_scatter<<<(EE * 32) / 256, 256, 0, stream>>>(ei, xw, dis, agg);

    // mean-pool + classifier
    k_final<<<BB, 128, 0, stream>>>(agg, g2b, clsw, clsb, out);
}

// Round 2
// 657.876 us; speedup vs baseline: 3.4774x; 3.4774x over previous
//
#include <hip/hip_runtime.h>
#include <hip/hip_bf16.h>

// Problem constants
#define BB    128
#define C_IN  9
#define T0    2048
#define T1    1024      // after pool1
#define T2    512       // after pool2
#define NN    65536     // B * T2 nodes
#define EE    524288    // edges
#define FEAT  32
#define HID   128
#define OUTC  6

// ---------------- conv1: [B,9,2048] -> relu -> pool2 -> h1 [B,16,1024] ----------------
__global__ __launch_bounds__(256) void k_conv1(const float* __restrict__ x,
                                               const float* __restrict__ w,
                                               const float* __restrict__ bias,
                                               float* __restrict__ h1) {
    int idx = blockIdx.x * 256 + threadIdx.x;          // over B*16*T1
    if (idx >= BB * 16 * T1) return;
    int tt = idx & (T1 - 1);
    int o  = (idx >> 10) & 15;
    int b  = idx >> 14;
    const float* xb = x + (size_t)b * C_IN * T0;
    const float* wo = w + o * C_IN * 5;
    float a0 = 0.f, a1 = 0.f;
    int t0 = 2 * tt;
    #pragma unroll
    for (int c = 0; c < C_IN; ++c) {
        const float* xc = xb + c * T0;
        #pragma unroll
        for (int k = 0; k < 5; ++k) {
            float wv = wo[c * 5 + k];
            int ta = t0 + k - 2;
            int tb = ta + 1;
            if ((unsigned)ta < T0) a0 += xc[ta] * wv;
            if ((unsigned)tb < T0) a1 += xc[tb] * wv;
        }
    }
    float bi = bias[o];
    a0 = fmaxf(a0 + bi, 0.f);
    a1 = fmaxf(a1 + bi, 0.f);
    h1[idx] = fmaxf(a0, a1);
}

// ---------------- conv2: h1 [B,16,1024] -> relu -> pool2 -> nodes [N,32] ----------------
__global__ __launch_bounds__(256) void k_conv2(const float* __restrict__ h1,
                                               const float* __restrict__ w,
                                               const float* __restrict__ bias,
                                               float* __restrict__ nodes) {
    int idx = blockIdx.x * 256 + threadIdx.x;          // over N*32
    if (idx >= NN * FEAT) return;
    int o    = idx & 31;
    int node = idx >> 5;
    int tt   = node & (T2 - 1);
    int b    = node >> 9;
    const float* hb = h1 + (size_t)b * 16 * T1;
    const float* wo = w + o * 16 * 5;
    float a0 = 0.f, a1 = 0.f;
    int t0 = 2 * tt;
    #pragma unroll
    for (int c = 0; c < 16; ++c) {
        const float* hc = hb + c * T1;
        #pragma unroll
        for (int k = 0; k < 5; ++k) {
            float wv = wo[c * 5 + k];
            int ta = t0 + k - 2;
            int tb = ta + 1;
            if ((unsigned)ta < T1) a0 += hc[ta] * wv;
            if ((unsigned)tb < T1) a1 += hc[tb] * wv;
        }
    }
    float bi = bias[o];
    a0 = fmaxf(a0 + bi, 0.f);
    a1 = fmaxf(a1 + bi, 0.f);
    nodes[idx] = fmaxf(a0, a1);
}

// ---------------- degree histogram at dst (int atomics) ----------------
__global__ __launch_bounds__(256) void k_deg(const int* __restrict__ ei,
                                             int* __restrict__ deg_i) {
    int e = blockIdx.x * 256 + threadIdx.x;
    if (e < EE) atomicAdd(&deg_i[ei[EE + e]], 1);
}

// ---------------- dis = rsqrt(deg+1) ----------------
__global__ __launch_bounds__(256) void k_dis(const int* __restrict__ deg_i,
                                             float* __restrict__ dis) {
    int n = blockIdx.x * 256 + threadIdx.x;
    if (n < NN) dis[n] = rsqrtf((float)deg_i[n] + 1.0f);
}

// ---------------- exclusive prefix scan of deg_i -> cursor (single block) ----------------
__global__ __launch_bounds__(1024) void k_scan(const int* __restrict__ deg_i,
                                               int* __restrict__ cursor) {
    __shared__ int part[1024];
    int t = threadIdx.x;
    int base = t * 64;
    int s = 0;
    for (int i = 0; i < 64; ++i) s += deg_i[base + i];
    part[t] = s;
    __syncthreads();
    for (int off = 1; off < 1024; off <<= 1) {
        int v = 0;
        if (t >= off) v = part[t - off];
        __syncthreads();
        if (t >= off) part[t] += v;
        __syncthreads();
    }
    int run = (t == 0) ? 0 : part[t - 1];
    for (int i = 0; i < 64; ++i) {
        cursor[base + i] = run;
        run += deg_i[base + i];
    }
}

// ---------------- fill CSR: csr_src[pos] = src (cursor advances to row end) ----------------
__global__ __launch_bounds__(256) void k_fill(const int* __restrict__ ei,
                                              int* __restrict__ cursor,
                                              int* __restrict__ csr_src) {
    int e = blockIdx.x * 256 + threadIdx.x;
    if (e >= EE) return;
    int s = ei[e];
    int d = ei[EE + e];
    int pos = atomicAdd(&cursor[d], 1);
    csr_src[pos] = s;
}

// ---------------- GCN1 GEMM: xws = (nodes @ W1) * dis[n] ----------------
#define NPB1 16
__global__ __launch_bounds__(256) void k_gemm1(const float* __restrict__ nodes,
                                               const float* __restrict__ w1,
                                               const float* __restrict__ dis,
                                               float* __restrict__ xws) {
    __shared__ float sw[FEAT * HID];       // 16 KiB
    __shared__ float srow[NPB1][FEAT];
    for (int i = threadIdx.x; i < FEAT * HID; i += 256) sw[i] = w1[i];
    int base = blockIdx.x * NPB1;
    for (int i = threadIdx.x; i < NPB1 * FEAT; i += 256)
        srow[i >> 5][i & 31] = nodes[(size_t)base * FEAT + i];
    __syncthreads();
    int o    = threadIdx.x & 127;
    int half = threadIdx.x >> 7;
    for (int j = half; j < NPB1; j += 2) {
        int n = base + j;
        float acc = 0.f;
        #pragma unroll
        for (int k = 0; k < FEAT; ++k) acc += srow[j][k] * sw[k * HID + o];
        xws[(size_t)n * HID + o] = acc * dis[n];
    }
}

// ---------------- gather: agg[d] = dis[d] * (xws[d] + sum_{incoming} xws[src]) ----------
// After k_fill, cursor[d] = row_end; row_beg = row_end - deg_i[d].
__global__ __launch_bounds__(256) void k_gather(const float* __restrict__ xws,
                                                const int* __restrict__ cursor,
                                                const int* __restrict__ deg_i,
                                                const int* __restrict__ csr_src,
                                                const float* __restrict__ dis,
                                                float* __restrict__ agg) {
    int t = blockIdx.x * 256 + threadIdx.x;
    int node = t >> 5;                    // 32 lanes per node (float4 each)
    if (node >= NN) return;
    int lane = t & 31;
    int end = cursor[node];
    int beg = end - deg_i[node];
    const float4* xv = (const float4*)xws;
    float4 acc = xv[(size_t)node * 32 + lane];   // self loop (xws already has dis[n])
    for (int j = beg; j < end; ++j) {
        int s = csr_src[j];
        float4 v = xv[(size_t)s * 32 + lane];
        acc.x += v.x; acc.y += v.y; acc.z += v.z; acc.w += v.w;
    }
    float dd = dis[node];
    float4 r; r.x = acc.x * dd; r.y = acc.y * dd; r.z = acc.z * dd; r.w = acc.w * dd;
    ((float4*)agg)[(size_t)node * 32 + lane] = r;
}

// ---------------- GCN2 GEMM: g = relu(agg1 + b1); xws2 = (g @ W2) * dis[n] --------------
#define NPB2 32
__global__ __launch_bounds__(256) void k_gemm2(const float* __restrict__ aggIn,
                                               const float* __restrict__ b1,
                                               const float* __restrict__ w2,
                                               const float* __restrict__ dis,
                                               float* __restrict__ xws2) {
    __shared__ float sw[HID * HID];        // 64 KiB
    __shared__ float srow[2][HID];
    for (int i = threadIdx.x; i < HID * HID; i += 256) sw[i] = w2[i];
    int o    = threadIdx.x & 127;
    int half = threadIdx.x >> 7;
    int base = blockIdx.x * NPB2;
    float bo = b1[o];
    for (int j = 0; j < NPB2; j += 2) {
        int n = base + j + half;
        __syncthreads();   // protect srow reuse from previous iteration (and sw on first)
        srow[half][o] = fmaxf(aggIn[(size_t)n * HID + o] + bo, 0.f);
        __syncthreads();
        float acc = 0.f;
        #pragma unroll
        for (int k = 0; k < HID; ++k) acc += srow[half][k] * sw[k * HID + o];
        xws2[(size_t)n * HID + o] = acc * dis[n];
    }
}

// ---------------- finalize: g2 = relu(agg2+b2); mean over T2; @ cls_w + cls_b ----------
__global__ __launch_bounds__(128) void k_final(const float* __restrict__ agg2,
                                               const float* __restrict__ b2,
                                               const float* __restrict__ clsw,
                                               const float* __restrict__ clsb,
                                               float* __restrict__ out) {
    __shared__ float pooled[HID];
    int b = blockIdx.x;
    int f = threadIdx.x;
    float bo = b2[f];
    float sum = 0.f;
    const float* basep = agg2 + (size_t)b * T2 * HID + f;
    for (int tt = 0; tt < T2; ++tt)
        sum += fmaxf(basep[(size_t)tt * HID] + bo, 0.f);
    pooled[f] = sum * (1.0f / (float)T2);
    __syncthreads();
    if (f < OUTC) {
        float acc = clsb[f];
        #pragma unroll 8
        for (int k = 0; k < HID; ++k) acc += pooled[k] * clsw[k * OUTC + f];
        out[b * OUTC + f] = acc;
    }
}

extern "C" void kernel_launch(void* const* d_in, const int* in_sizes, int n_in,
                              void* d_out, int out_size, void* d_ws, size_t ws_size,
                              hipStream_t stream) {
    const float* x    = (const float*)d_in[0];
    const int*   ei   = (const int*)d_in[1];
    const float* c1w  = (const float*)d_in[2];
    const float* c1b  = (const float*)d_in[3];
    const float* c2w  = (const float*)d_in[4];
    const float* c2b  = (const float*)d_in[5];
    const float* g1w  = (const float*)d_in[6];
    const float* g1b  = (const float*)d_in[7];
    const float* g2w  = (const float*)d_in[8];
    const float* g2b  = (const float*)d_in[9];
    const float* clsw = (const float*)d_in[10];
    const float* clsb = (const float*)d_in[11];
    float* out = (float*)d_out;

    float* ws = (float*)d_ws;
    // element offsets (floats); h1 overlays xws (dead before gemm1 writes xws)
    float* xws   = ws;                       // [0, 8388608)
    float* h1    = ws;
    float* agg   = ws + 8388608;             // [8388608, 16777216)
    float* nodes = ws + 16777216;            // [16777216, 18874368)
    float* dis   = ws + 18874368;            // [18874368, 18939904)
    int* deg_i   = (int*)(ws + 18939904);    // 65536 ints
    int* cursor  = (int*)(ws + 19005440);    // 65536 ints
    int* csr_src = (int*)(ws + 19070976);    // 524288 ints
    // total 19595264 * 4 B = 78.4 MB

    hipMemsetAsync(deg_i, 0, NN * sizeof(int), stream);

    // temporal conv stack
    k_conv1<<<(BB * 16 * T1) / 256, 256, 0, stream>>>(x, c1w, c1b, h1);
    k_conv2<<<(NN * FEAT) / 256, 256, 0, stream>>>(h1, c2w, c2b, nodes);

    // CSR build (dst-indexed incoming-edge lists) + normalization
    k_deg <<<(EE + 255) / 256, 256, 0, stream>>>(ei, deg_i);
    k_scan<<<1, 1024, 0, stream>>>(deg_i, cursor);
    k_fill<<<(EE + 255) / 256, 256, 0, stream>>>(ei, cursor, csr_src);
    k_dis <<<(NN + 255) / 256, 256, 0, stream>>>(deg_i, dis);

    // GCN layer 1
    k_gemm1 <<<NN / NPB1, 256, 0, stream>>>(nodes, g1w, dis, xws);
    k_gather<<<(NN * 32) / 256, 256, 0, stream>>>(xws, cursor, deg_i, csr_src, dis, agg);

    // GCN layer 2
    k_gemm2 <<<NN / NPB2, 256, 0, stream>>>(agg, g1b, g2w, dis, xws);
    k_gather<<<(NN * 32) / 256, 256, 0, stream>>>(xws, cursor, deg_i, csr_src, dis, agg);

    // mean-pool + classifier
    k_final<<<BB, 128, 0, stream>>>(agg, g2b, clsw, clsb, out);
}

// Round 3
// 388.754 us; speedup vs baseline: 5.8847x; 1.6923x over previous
//
#include <hip/hip_runtime.h>
#include <hip/hip_bf16.h>

// Problem constants
#define BB    128
#define C_IN  9
#define T0    2048
#define T1    1024      // after pool1
#define T2    512       // after pool2
#define NN    65536     // B * T2 nodes
#define EE    524288    // edges
#define FEAT  32
#define HID   128
#define OUTC  6

// ---------------- conv1: [B,9,2048] -> relu -> pool2 -> h1 [B,16,1024] ----------------
__global__ __launch_bounds__(256) void k_conv1(const float* __restrict__ x,
                                               const float* __restrict__ w,
                                               const float* __restrict__ bias,
                                               float* __restrict__ h1) {
    int idx = blockIdx.x * 256 + threadIdx.x;          // over B*16*T1, tt fastest
    int tt = idx & (T1 - 1);
    int o  = (idx >> 10) & 15;
    int b  = idx >> 14;
    const float* xb = x + (size_t)b * C_IN * T0;
    const float* wo = w + o * C_IN * 5;
    float a0 = 0.f, a1 = 0.f;
    int t0 = 2 * tt;
    #pragma unroll
    for (int c = 0; c < C_IN; ++c) {
        const float* xc = xb + c * T0;
        float v0 = 0.f, v1 = 0.f, v4 = 0.f, v5 = 0.f;
        if (tt > 0) { float2 p = *(const float2*)(xc + t0 - 2); v0 = p.x; v1 = p.y; }
        float2 pm = *(const float2*)(xc + t0);
        float v2 = pm.x, v3 = pm.y;
        if (tt < T1 - 1) { float2 p = *(const float2*)(xc + t0 + 2); v4 = p.x; v5 = p.y; }
        const float* wc = wo + c * 5;
        float w0 = wc[0], w1 = wc[1], w2 = wc[2], w3 = wc[3], w4 = wc[4];
        a0 += w0 * v0 + w1 * v1 + w2 * v2 + w3 * v3 + w4 * v4;
        a1 += w0 * v1 + w1 * v2 + w2 * v3 + w3 * v4 + w4 * v5;
    }
    float bi = bias[o];
    a0 = fmaxf(a0 + bi, 0.f);
    a1 = fmaxf(a1 + bi, 0.f);
    h1[idx] = fmaxf(a0, a1);
}

// ---------------- conv2: h1 [B,16,1024] -> relu -> pool2 -> nodes [N,32] ----------------
// tt fastest within wave: weights wave-uniform, h1 loads coalesced.
__global__ __launch_bounds__(256) void k_conv2(const float* __restrict__ h1,
                                               const float* __restrict__ w,
                                               const float* __restrict__ bias,
                                               float* __restrict__ nodes) {
    int idx = blockIdx.x * 256 + threadIdx.x;          // over B*32*T2
    int tt = idx & (T2 - 1);
    int o  = (idx >> 9) & 31;
    int b  = idx >> 14;
    const float* hb = h1 + (size_t)b * 16 * T1;
    const float* wo = w + o * 16 * 5;
    float a0 = 0.f, a1 = 0.f;
    int t0 = 2 * tt;
    #pragma unroll
    for (int c = 0; c < 16; ++c) {
        const float* hc = hb + c * T1;
        float v0 = 0.f, v1 = 0.f, v4 = 0.f, v5 = 0.f;
        if (tt > 0) { float2 p = *(const float2*)(hc + t0 - 2); v0 = p.x; v1 = p.y; }
        float2 pm = *(const float2*)(hc + t0);
        float v2 = pm.x, v3 = pm.y;
        if (tt < T2 - 1) { float2 p = *(const float2*)(hc + t0 + 2); v4 = p.x; v5 = p.y; }
        const float* wc = wo + c * 5;
        float w0 = wc[0], w1 = wc[1], w2 = wc[2], w3 = wc[3], w4 = wc[4];
        a0 += w0 * v0 + w1 * v1 + w2 * v2 + w3 * v3 + w4 * v4;
        a1 += w0 * v1 + w1 * v2 + w2 * v3 + w3 * v4 + w4 * v5;
    }
    float bi = bias[o];
    a0 = fmaxf(a0 + bi, 0.f);
    a1 = fmaxf(a1 + bi, 0.f);
    nodes[(size_t)(b * T2 + tt) * FEAT + o] = fmaxf(a0, a1);
}

// ---------------- degree histogram at dst (int atomics) ----------------
__global__ __launch_bounds__(256) void k_deg(const int* __restrict__ ei,
                                             int* __restrict__ deg_i) {
    int e = blockIdx.x * 256 + threadIdx.x;
    if (e < EE) atomicAdd(&deg_i[ei[EE + e]], 1);
}

__global__ __launch_bounds__(256) void k_dis(const int* __restrict__ deg_i,
                                             float* __restrict__ dis) {
    int n = blockIdx.x * 256 + threadIdx.x;
    if (n < NN) dis[n] = rsqrtf((float)deg_i[n] + 1.0f);
}

// ---------------- exclusive prefix scan of deg_i -> cursor (single block) ----------------
__global__ __launch_bounds__(1024) void k_scan(const int* __restrict__ deg_i,
                                               int* __restrict__ cursor) {
    __shared__ int part[1024];
    int t = threadIdx.x;
    int base = t * 64;
    int s = 0;
    for (int i = 0; i < 64; ++i) s += deg_i[base + i];
    part[t] = s;
    __syncthreads();
    for (int off = 1; off < 1024; off <<= 1) {
        int v = 0;
        if (t >= off) v = part[t - off];
        __syncthreads();
        if (t >= off) part[t] += v;
        __syncthreads();
    }
    int run = (t == 0) ? 0 : part[t - 1];
    for (int i = 0; i < 64; ++i) {
        cursor[base + i] = run;
        run += deg_i[base + i];
    }
}

// ---------------- fill CSR ----------------
__global__ __launch_bounds__(256) void k_fill(const int* __restrict__ ei,
                                              int* __restrict__ cursor,
                                              int* __restrict__ csr_src) {
    int e = blockIdx.x * 256 + threadIdx.x;
    if (e >= EE) return;
    int s = ei[e];
    int d = ei[EE + e];
    int pos = atomicAdd(&cursor[d], 1);
    csr_src[pos] = s;
}

// ---------------- register-tiled GEMM: out[n][o] = (relu(A[n]+bias)? @ W)[o] * dis[n] ---
// Block tile 128 rows x 128 cols, thread tile 8x8, K chunks of 32, double-buffered LDS.
template<int K, bool RELU_BIAS>
__global__ __launch_bounds__(256) void k_gemm(const float* __restrict__ A,
                                              const float* __restrict__ W,     // [K][HID]
                                              const float* __restrict__ bias,  // [K] or null
                                              const float* __restrict__ dis,
                                              float* __restrict__ out) {
    constexpr int KC = 32;
    constexpr int CHUNKS = K / KC;
    __shared__ float sA[2][KC][128 + 4];   // k-major, 16B-aligned pad
    __shared__ float sB[2][KC][128 + 4];
    int tid = threadIdx.x;
    int rowBase = blockIdx.x * 128;
    int tr = tid >> 4;          // 0..15 -> rows tr*8..tr*8+7
    int tc = tid & 15;          // cols tc*8..tc*8+7

    float acc[8][8];
    #pragma unroll
    for (int i = 0; i < 8; ++i)
        #pragma unroll
        for (int j = 0; j < 8; ++j) acc[i][j] = 0.f;

    int ar = tid & 127;         // staging row
    int aq = (tid >> 7) * 4;    // staging quad base (2 halves of 32-k chunk)

    // ---- stage chunk cc into buffer bb ----
    auto stage = [&](int cc, int bb) {
        // A: 128 rows x 32 k -> sA[k][row]
        const float* arow = A + (size_t)(rowBase + ar) * K + cc * KC + aq * 4;
        #pragma unroll
        for (int q = 0; q < 4; ++q) {
            float4 va = *(const float4*)(arow + q * 4);
            if (RELU_BIAS) {
                float4 vb = *(const float4*)(bias + cc * KC + (aq + q) * 4);
                va.x = fmaxf(va.x + vb.x, 0.f);
                va.y = fmaxf(va.y + vb.y, 0.f);
                va.z = fmaxf(va.z + vb.z, 0.f);
                va.w = fmaxf(va.w + vb.w, 0.f);
            }
            int kb = (aq + q) * 4;
            sA[bb][kb + 0][ar] = va.x;
            sA[bb][kb + 1][ar] = va.y;
            sA[bb][kb + 2][ar] = va.z;
            sA[bb][kb + 3][ar] = va.w;
        }
        // B: 32 k x 128 cols -> sB[k][c] (same layout as W)
        #pragma unroll
        for (int it = 0; it < 4; ++it) {
            int i = tid + it * 256;          // 0..1023 float4s
            int k  = i >> 5;
            int c4 = (i & 31) * 4;
            *(float4*)&sB[bb][k][c4] = *(const float4*)(W + (size_t)(cc * KC + k) * HID + c4);
        }
    };

    stage(0, 0);
    __syncthreads();
    for (int cc = 0; cc < CHUNKS; ++cc) {
        if (cc + 1 < CHUNKS) stage(cc + 1, (cc + 1) & 1);
        int bb = cc & 1;
        #pragma unroll 8
        for (int k = 0; k < KC; ++k) {
            float4 a0 = *(const float4*)&sA[bb][k][tr * 8];
            float4 a1 = *(const float4*)&sA[bb][k][tr * 8 + 4];
            float4 b0 = *(const float4*)&sB[bb][k][tc * 8];
            float4 b1 = *(const float4*)&sB[bb][k][tc * 8 + 4];
            float av[8] = {a0.x, a0.y, a0.z, a0.w, a1.x, a1.y, a1.z, a1.w};
            float bv[8] = {b0.x, b0.y, b0.z, b0.w, b1.x, b1.y, b1.z, b1.w};
            #pragma unroll
            for (int i = 0; i < 8; ++i)
                #pragma unroll
                for (int j = 0; j < 8; ++j) acc[i][j] += av[i] * bv[j];
        }
        __syncthreads();
    }

    #pragma unroll
    for (int i = 0; i < 8; ++i) {
        int row = rowBase + tr * 8 + i;
        float d = dis[row];
        float4 o0, o1;
        o0.x = acc[i][0] * d; o0.y = acc[i][1] * d; o0.z = acc[i][2] * d; o0.w = acc[i][3] * d;
        o1.x = acc[i][4] * d; o1.y = acc[i][5] * d; o1.z = acc[i][6] * d; o1.w = acc[i][7] * d;
        float* op = out + (size_t)row * HID + tc * 8;
        *(float4*)op       = o0;
        *(float4*)(op + 4) = o1;
    }
}

// ---------------- gather: agg[d] = dis[d] * (xws[d] + sum_{incoming} xws[src]) ----------
__global__ __launch_bounds__(256) void k_gather(const float* __restrict__ xws,
                                                const int* __restrict__ cursor,
                                                const int* __restrict__ deg_i,
                                                const int* __restrict__ csr_src,
                                                const float* __restrict__ dis,
                                                float* __restrict__ agg) {
    int t = blockIdx.x * 256 + threadIdx.x;
    int node = t >> 5;                    // 32 lanes per node (float4 each)
    if (node >= NN) return;
    int lane = t & 31;
    int end = cursor[node];
    int beg = end - deg_i[node];
    const float4* xv = (const float4*)xws;
    float4 acc = xv[(size_t)node * 32 + lane];   // self loop
    for (int j = beg; j < end; ++j) {
        int s = csr_src[j];
        float4 v = xv[(size_t)s * 32 + lane];
        acc.x += v.x; acc.y += v.y; acc.z += v.z; acc.w += v.w;
    }
    float dd = dis[node];
    float4 r; r.x = acc.x * dd; r.y = acc.y * dd; r.z = acc.z * dd; r.w = acc.w * dd;
    ((float4*)agg)[(size_t)node * 32 + lane] = r;
}

// ---------------- finalize: g2 = relu(agg2+b2); mean over T2; @ cls_w + cls_b ----------
__global__ __launch_bounds__(128) void k_final(const float* __restrict__ agg2,
                                               const float* __restrict__ b2,
                                               const float* __restrict__ clsw,
                                               const float* __restrict__ clsb,
                                               float* __restrict__ out) {
    __shared__ float pooled[HID];
    int b = blockIdx.x;
    int f = threadIdx.x;
    float bo = b2[f];
    float sum = 0.f;
    const float* basep = agg2 + (size_t)b * T2 * HID + f;
    for (int tt = 0; tt < T2; ++tt)
        sum += fmaxf(basep[(size_t)tt * HID] + bo, 0.f);
    pooled[f] = sum * (1.0f / (float)T2);
    __syncthreads();
    if (f < OUTC) {
        float acc = clsb[f];
        #pragma unroll 8
        for (int k = 0; k < HID; ++k) acc += pooled[k] * clsw[k * OUTC + f];
        out[b * OUTC + f] = acc;
    }
}

extern "C" void kernel_launch(void* const* d_in, const int* in_sizes, int n_in,
                              void* d_out, int out_size, void* d_ws, size_t ws_size,
                              hipStream_t stream) {
    const float* x    = (const float*)d_in[0];
    const int*   ei   = (const int*)d_in[1];
    const float* c1w  = (const float*)d_in[2];
    const float* c1b  = (const float*)d_in[3];
    const float* c2w  = (const float*)d_in[4];
    const float* c2b  = (const float*)d_in[5];
    const float* g1w  = (const float*)d_in[6];
    const float* g1b  = (const float*)d_in[7];
    const float* g2w  = (const float*)d_in[8];
    const float* g2b  = (const float*)d_in[9];
    const float* clsw = (const float*)d_in[10];
    const float* clsb = (const float*)d_in[11];
    float* out = (float*)d_out;

    float* ws = (float*)d_ws;
    // element offsets (floats); h1 overlays xws (dead before gemm1 writes xws)
    float* xws   = ws;                       // [0, 8388608)
    float* h1    = ws;
    float* agg   = ws + 8388608;             // [8388608, 16777216)
    float* nodes = ws + 16777216;            // [16777216, 18874368)
    float* dis   = ws + 18874368;            // [18874368, 18939904)
    int* deg_i   = (int*)(ws + 18939904);    // 65536 ints
    int* cursor  = (int*)(ws + 19005440);    // 65536 ints
    int* csr_src = (int*)(ws + 19070976);    // 524288 ints

    hipMemsetAsync(deg_i, 0, NN * sizeof(int), stream);

    // temporal conv stack
    k_conv1<<<(BB * 16 * T1) / 256, 256, 0, stream>>>(x, c1w, c1b, h1);
    k_conv2<<<(BB * 32 * T2) / 256, 256, 0, stream>>>(h1, c2w, c2b, nodes);

    // CSR build + normalization
    k_deg <<<(EE + 255) / 256, 256, 0, stream>>>(ei, deg_i);
    k_scan<<<1, 1024, 0, stream>>>(deg_i, cursor);
    k_fill<<<(EE + 255) / 256, 256, 0, stream>>>(ei, cursor, csr_src);
    k_dis <<<(NN + 255) / 256, 256, 0, stream>>>(deg_i, dis);

    // GCN layer 1: xws = (nodes @ W1) * dis
    k_gemm<FEAT, false><<<NN / 128, 256, 0, stream>>>(nodes, g1w, nullptr, dis, xws);
    k_gather<<<(NN * 32) / 256, 256, 0, stream>>>(xws, cursor, deg_i, csr_src, dis, agg);

    // GCN layer 2: xws = (relu(agg + b1) @ W2) * dis
    k_gemm<HID, true><<<NN / 128, 256, 0, stream>>>(agg, g2w, g1b, dis, xws);
    k_gather<<<(NN * 32) / 256, 256, 0, stream>>>(xws, cursor, deg_i, csr_src, dis, agg);

    // mean-pool + classifier
    k_final<<<BB, 128, 0, stream>>>(agg, g2b, clsw, clsb, out);
}

// Round 4
// 280.643 us; speedup vs baseline: 8.1517x; 1.3852x over previous
//
#include <hip/hip_runtime.h>
#include <hip/hip_bf16.h>

// Problem constants
#define BB    128
#define C_IN  9
#define T0    2048
#define T1    1024      // after pool1
#define T2    512       // after pool2
#define NN    65536     // B * T2 nodes
#define EE    524288    // edges
#define FEAT  32
#define HID   128
#define OUTC  6

// ---------------- conv1 (LDS-tiled): x [B,9,2048] -> relu -> pool2 -> h1 [B,16,1024] ---
// Block = (b, 1/8 of T1). Lane mapping: o = lane&15, slot = lane>>4 (8-tt groups).
// Weights staged [c][k][o] (conflict-free lane reads); inputs broadcast within slot.
__global__ __launch_bounds__(256) void k_conv1(const float* __restrict__ x,
                                               const float* __restrict__ w,
                                               const float* __restrict__ bias,
                                               float* __restrict__ h1) {
    __shared__ float sx[C_IN][264];       // 260 used (256 pre-pool + 4 halo), pad->264
    __shared__ float swt[45 * 16];        // [c*5+k][o]
    int b   = blockIdx.x >> 3;
    int qt  = blockIdx.x & 7;             // 128 T1-outputs per tile
    int tid = threadIdx.x;

    const float* xb = x + (size_t)b * C_IN * T0;
    int gbase = qt * 256 - 2;
    #pragma unroll
    for (int c = 0; c < C_IN; ++c)
        for (int i = tid; i < 260; i += 256) {
            int g = gbase + i;
            sx[c][i] = ((unsigned)g < T0) ? xb[c * T0 + g] : 0.f;
        }
    for (int idx = tid; idx < 720; idx += 256) {
        int o = idx & 15, ck = idx >> 4;
        swt[ck * 16 + o] = w[o * 45 + ck];
    }
    __syncthreads();

    int lane = tid & 63;
    int wv   = tid >> 6;
    int o    = lane & 15;
    int slot = lane >> 4;
    int ttl0 = wv * 32 + slot * 8;        // tile-local tt base, 8 outputs/lane

    float acc[16];
    #pragma unroll
    for (int i = 0; i < 16; ++i) acc[i] = 0.f;

    #pragma unroll
    for (int c = 0; c < C_IN; ++c) {
        float wt[5];
        #pragma unroll
        for (int k = 0; k < 5; ++k) wt[k] = swt[(c * 5 + k) * 16 + o];
        #pragma unroll
        for (int cb = 0; cb < 2; ++cb) {
            int Pb = 2 * ttl0 + 8 * cb;
            float4 i0 = *(const float4*)&sx[c][Pb];
            float4 i1 = *(const float4*)&sx[c][Pb + 4];
            float4 i2 = *(const float4*)&sx[c][Pb + 8];
            float in[12] = {i0.x,i0.y,i0.z,i0.w, i1.x,i1.y,i1.z,i1.w, i2.x,i2.y,i2.z,i2.w};
            #pragma unroll
            for (int q = 0; q < 8; ++q) {
                float s = acc[cb * 8 + q];
                #pragma unroll
                for (int k = 0; k < 5; ++k) s += wt[k] * in[q + k];
                acc[cb * 8 + q] = s;
            }
        }
    }

    float bi = bias[o];
    float* hp = h1 + (size_t)(b * 16 + o) * T1 + qt * 128 + ttl0;
    #pragma unroll
    for (int cb = 0; cb < 2; ++cb) {
        float4 r;
        r.x = fmaxf(fmaxf(acc[cb*8+0], acc[cb*8+1]) + bi, 0.f);
        r.y = fmaxf(fmaxf(acc[cb*8+2], acc[cb*8+3]) + bi, 0.f);
        r.z = fmaxf(fmaxf(acc[cb*8+4], acc[cb*8+5]) + bi, 0.f);
        r.w = fmaxf(fmaxf(acc[cb*8+6], acc[cb*8+7]) + bi, 0.f);
        *(float4*)(hp + cb * 4) = r;
    }
}

// ---------------- conv2 (LDS-tiled): h1 -> relu -> pool2 -> nodes [N,32] ----------------
// Block = (b, 1/8 of T2). Lane: o = lane&31, slot = lane>>5. Stores fully coalesced.
__global__ __launch_bounds__(256) void k_conv2(const float* __restrict__ h1,
                                               const float* __restrict__ w,
                                               const float* __restrict__ bias,
                                               float* __restrict__ nodes) {
    __shared__ float sh[16][136];         // 132 used (128 pre-pool + 4 halo), pad->136
    __shared__ float swt[80 * 32];        // [c*5+k][o], 10 KiB
    int b   = blockIdx.x >> 3;
    int qt  = blockIdx.x & 7;             // 64 T2-outputs per tile
    int tid = threadIdx.x;

    const float* hb = h1 + (size_t)b * 16 * T1;
    int gbase = qt * 128 - 2;
    #pragma unroll
    for (int c = 0; c < 16; ++c)
        for (int i = tid; i < 132; i += 256) {
            int g = gbase + i;
            sh[c][i] = ((unsigned)g < T1) ? hb[c * T1 + g] : 0.f;
        }
    for (int idx = tid; idx < 2560; idx += 256) {
        int o = idx & 31, ck = idx >> 5;
        swt[ck * 32 + o] = w[o * 80 + ck];
    }
    __syncthreads();

    int lane = tid & 63;
    int wv   = tid >> 6;
    int o    = lane & 31;
    int slot = lane >> 5;
    int ttl0 = wv * 16 + slot * 8;        // tile-local tt base, 8 outputs/lane

    float acc[16];
    #pragma unroll
    for (int i = 0; i < 16; ++i) acc[i] = 0.f;

    #pragma unroll
    for (int c = 0; c < 16; ++c) {
        float wt[5];
        #pragma unroll
        for (int k = 0; k < 5; ++k) wt[k] = swt[(c * 5 + k) * 32 + o];
        #pragma unroll
        for (int cb = 0; cb < 2; ++cb) {
            int Pb = 2 * ttl0 + 8 * cb;
            float4 i0 = *(const float4*)&sh[c][Pb];
            float4 i1 = *(const float4*)&sh[c][Pb + 4];
            float4 i2 = *(const float4*)&sh[c][Pb + 8];
            float in[12] = {i0.x,i0.y,i0.z,i0.w, i1.x,i1.y,i1.z,i1.w, i2.x,i2.y,i2.z,i2.w};
            #pragma unroll
            for (int q = 0; q < 8; ++q) {
                float s = acc[cb * 8 + q];
                #pragma unroll
                for (int k = 0; k < 5; ++k) s += wt[k] * in[q + k];
                acc[cb * 8 + q] = s;
            }
        }
    }

    float bi = bias[o];
    size_t nbase = ((size_t)b * T2 + qt * 64 + ttl0) * FEAT + o;
    #pragma unroll
    for (int cb = 0; cb < 2; ++cb)
        #pragma unroll
        for (int jj = 0; jj < 4; ++jj) {
            float v = fmaxf(fmaxf(acc[cb*8+2*jj], acc[cb*8+2*jj+1]) + bi, 0.f);
            nodes[nbase + (size_t)(cb * 4 + jj) * FEAT] = v;
        }
}

// ---------------- degree histogram at dst (int atomics) ----------------
__global__ __launch_bounds__(256) void k_deg(const int* __restrict__ ei,
                                             int* __restrict__ deg_i) {
    int e = blockIdx.x * 256 + threadIdx.x;
    if (e < EE) atomicAdd(&deg_i[ei[EE + e]], 1);
}

__global__ __launch_bounds__(256) void k_dis(const int* __restrict__ deg_i,
                                             float* __restrict__ dis) {
    int n = blockIdx.x * 256 + threadIdx.x;
    if (n < NN) dis[n] = rsqrtf((float)deg_i[n] + 1.0f);
}

// ---------------- exclusive prefix scan of deg_i -> cursor (single block) ----------------
__global__ __launch_bounds__(1024) void k_scan(const int* __restrict__ deg_i,
                                               int* __restrict__ cursor) {
    __shared__ int part[1024];
    int t = threadIdx.x;
    int base = t * 64;
    int s = 0;
    for (int i = 0; i < 64; ++i) s += deg_i[base + i];
    part[t] = s;
    __syncthreads();
    for (int off = 1; off < 1024; off <<= 1) {
        int v = 0;
        if (t >= off) v = part[t - off];
        __syncthreads();
        if (t >= off) part[t] += v;
        __syncthreads();
    }
    int run = (t == 0) ? 0 : part[t - 1];
    for (int i = 0; i < 64; ++i) {
        cursor[base + i] = run;
        run += deg_i[base + i];
    }
}

// ---------------- fill CSR ----------------
__global__ __launch_bounds__(256) void k_fill(const int* __restrict__ ei,
                                              int* __restrict__ cursor,
                                              int* __restrict__ csr_src) {
    int e = blockIdx.x * 256 + threadIdx.x;
    if (e >= EE) return;
    int s = ei[e];
    int d = ei[EE + e];
    int pos = atomicAdd(&cursor[d], 1);
    csr_src[pos] = s;
}

// ---------------- register-tiled GEMM: out[n][o] = (relu(A[n]+bias)? @ W)[o] * dis[n] ---
template<int K, bool RELU_BIAS>
__global__ __launch_bounds__(256) void k_gemm(const float* __restrict__ A,
                                              const float* __restrict__ W,     // [K][HID]
                                              const float* __restrict__ bias,  // [K] or null
                                              const float* __restrict__ dis,
                                              float* __restrict__ out) {
    constexpr int KC = 32;
    constexpr int CHUNKS = K / KC;
    __shared__ float sA[2][KC][128 + 4];
    __shared__ float sB[2][KC][128 + 4];
    int tid = threadIdx.x;
    int rowBase = blockIdx.x * 128;
    int tr = tid >> 4;
    int tc = tid & 15;

    float acc[8][8];
    #pragma unroll
    for (int i = 0; i < 8; ++i)
        #pragma unroll
        for (int j = 0; j < 8; ++j) acc[i][j] = 0.f;

    int ar = tid & 127;
    int aq = (tid >> 7) * 4;

    auto stage = [&](int cc, int bb) {
        const float* arow = A + (size_t)(rowBase + ar) * K + cc * KC + aq * 4;
        #pragma unroll
        for (int q = 0; q < 4; ++q) {
            float4 va = *(const float4*)(arow + q * 4);
            if (RELU_BIAS) {
                float4 vb = *(const float4*)(bias + cc * KC + (aq + q) * 4);
                va.x = fmaxf(va.x + vb.x, 0.f);
                va.y = fmaxf(va.y + vb.y, 0.f);
                va.z = fmaxf(va.z + vb.z, 0.f);
                va.w = fmaxf(va.w + vb.w, 0.f);
            }
            int kb = (aq + q) * 4;
            sA[bb][kb + 0][ar] = va.x;
            sA[bb][kb + 1][ar] = va.y;
            sA[bb][kb + 2][ar] = va.z;
            sA[bb][kb + 3][ar] = va.w;
        }
        #pragma unroll
        for (int it = 0; it < 4; ++it) {
            int i = tid + it * 256;
            int k  = i >> 5;
            int c4 = (i & 31) * 4;
            *(float4*)&sB[bb][k][c4] = *(const float4*)(W + (size_t)(cc * KC + k) * HID + c4);
        }
    };

    stage(0, 0);
    __syncthreads();
    for (int cc = 0; cc < CHUNKS; ++cc) {
        if (cc + 1 < CHUNKS) stage(cc + 1, (cc + 1) & 1);
        int bb = cc & 1;
        #pragma unroll 8
        for (int k = 0; k < KC; ++k) {
            float4 a0 = *(const float4*)&sA[bb][k][tr * 8];
            float4 a1 = *(const float4*)&sA[bb][k][tr * 8 + 4];
            float4 b0 = *(const float4*)&sB[bb][k][tc * 8];
            float4 b1 = *(const float4*)&sB[bb][k][tc * 8 + 4];
            float av[8] = {a0.x, a0.y, a0.z, a0.w, a1.x, a1.y, a1.z, a1.w};
            float bv[8] = {b0.x, b0.y, b0.z, b0.w, b1.x, b1.y, b1.z, b1.w};
            #pragma unroll
            for (int i = 0; i < 8; ++i)
                #pragma unroll
                for (int j = 0; j < 8; ++j) acc[i][j] += av[i] * bv[j];
        }
        __syncthreads();
    }

    #pragma unroll
    for (int i = 0; i < 8; ++i) {
        int row = rowBase + tr * 8 + i;
        float d = dis[row];
        float4 o0, o1;
        o0.x = acc[i][0] * d; o0.y = acc[i][1] * d; o0.z = acc[i][2] * d; o0.w = acc[i][3] * d;
        o1.x = acc[i][4] * d; o1.y = acc[i][5] * d; o1.z = acc[i][6] * d; o1.w = acc[i][7] * d;
        float* op = out + (size_t)row * HID + tc * 8;
        *(float4*)op       = o0;
        *(float4*)(op + 4) = o1;
    }
}

// ---------------- gather: agg[d] = dis[d] * (xws[d] + sum_{incoming} xws[src]) ----------
__global__ __launch_bounds__(256) void k_gather(const float* __restrict__ xws,
                                                const int* __restrict__ cursor,
                                                const int* __restrict__ deg_i,
                                                const int* __restrict__ csr_src,
                                                const float* __restrict__ dis,
                                                float* __restrict__ agg) {
    int t = blockIdx.x * 256 + threadIdx.x;
    int node = t >> 5;
    if (node >= NN) return;
    int lane = t & 31;
    int end = cursor[node];
    int beg = end - deg_i[node];
    const float4* xv = (const float4*)xws;
    float4 acc = xv[(size_t)node * 32 + lane];
    for (int j = beg; j < end; ++j) {
        int s = csr_src[j];
        float4 v = xv[(size_t)s * 32 + lane];
        acc.x += v.x; acc.y += v.y; acc.z += v.z; acc.w += v.w;
    }
    float dd = dis[node];
    float4 r; r.x = acc.x * dd; r.y = acc.y * dd; r.z = acc.z * dd; r.w = acc.w * dd;
    ((float4*)agg)[(size_t)node * 32 + lane] = r;
}

// ---------------- finalize ----------------
__global__ __launch_bounds__(128) void k_final(const float* __restrict__ agg2,
                                               const float* __restrict__ b2,
                                               const float* __restrict__ clsw,
                                               const float* __restrict__ clsb,
                                               float* __restrict__ out) {
    __shared__ float pooled[HID];
    int b = blockIdx.x;
    int f = threadIdx.x;
    float bo = b2[f];
    float sum = 0.f;
    const float* basep = agg2 + (size_t)b * T2 * HID + f;
    for (int tt = 0; tt < T2; ++tt)
        sum += fmaxf(basep[(size_t)tt * HID] + bo, 0.f);
    pooled[f] = sum * (1.0f / (float)T2);
    __syncthreads();
    if (f < OUTC) {
        float acc = clsb[f];
        #pragma unroll 8
        for (int k = 0; k < HID; ++k) acc += pooled[k] * clsw[k * OUTC + f];
        out[b * OUTC + f] = acc;
    }
}

extern "C" void kernel_launch(void* const* d_in, const int* in_sizes, int n_in,
                              void* d_out, int out_size, void* d_ws, size_t ws_size,
                              hipStream_t stream) {
    const float* x    = (const float*)d_in[0];
    const int*   ei   = (const int*)d_in[1];
    const float* c1w  = (const float*)d_in[2];
    const float* c1b  = (const float*)d_in[3];
    const float* c2w  = (const float*)d_in[4];
    const float* c2b  = (const float*)d_in[5];
    const float* g1w  = (const float*)d_in[6];
    const float* g1b  = (const float*)d_in[7];
    const float* g2w  = (const float*)d_in[8];
    const float* g2b  = (const float*)d_in[9];
    const float* clsw = (const float*)d_in[10];
    const float* clsb = (const float*)d_in[11];
    float* out = (float*)d_out;

    float* ws = (float*)d_ws;
    float* xws   = ws;                       // [0, 8388608)
    float* h1    = ws;                       // overlays xws (dead before gemm1)
    float* agg   = ws + 8388608;             // [8388608, 16777216)
    float* nodes = ws + 16777216;            // [16777216, 18874368)
    float* dis   = ws + 18874368;
    int* deg_i   = (int*)(ws + 18939904);
    int* cursor  = (int*)(ws + 19005440);
    int* csr_src = (int*)(ws + 19070976);

    hipMemsetAsync(deg_i, 0, NN * sizeof(int), stream);

    // temporal conv stack (LDS-tiled)
    k_conv1<<<BB * 8, 256, 0, stream>>>(x, c1w, c1b, h1);
    k_conv2<<<BB * 8, 256, 0, stream>>>(h1, c2w, c2b, nodes);

    // CSR build + normalization
    k_deg <<<(EE + 255) / 256, 256, 0, stream>>>(ei, deg_i);
    k_scan<<<1, 1024, 0, stream>>>(deg_i, cursor);
    k_fill<<<(EE + 255) / 256, 256, 0, stream>>>(ei, cursor, csr_src);
    k_dis <<<(NN + 255) / 256, 256, 0, stream>>>(deg_i, dis);

    // GCN layer 1: xws = (nodes @ W1) * dis
    k_gemm<FEAT, false><<<NN / 128, 256, 0, stream>>>(nodes, g1w, nullptr, dis, xws);
    k_gather<<<(NN * 32) / 256, 256, 0, stream>>>(xws, cursor, deg_i, csr_src, dis, agg);

    // GCN layer 2: xws = (relu(agg + b1) @ W2) * dis
    k_gemm<HID, true><<<NN / 128, 256, 0, stream>>>(agg, g2w, g1b, dis, xws);
    k_gather<<<(NN * 32) / 256, 256, 0, stream>>>(xws, cursor, deg_i, csr_src, dis, agg);

    // mean-pool + classifier
    k_final<<<BB, 128, 0, stream>>>(agg, g2b, clsw, clsb, out);
}

// Round 5
// 228.062 us; speedup vs baseline: 10.0311x; 1.2306x over previous
//
#include <hip/hip_runtime.h>
#include <hip/hip_bf16.h>

// Problem constants
#define BB    128
#define C_IN  9
#define T0    2048
#define T1    1024      // after pool1
#define T2    512       // after pool2
#define NN    65536     // B * T2 nodes
#define EE    524288    // edges
#define FEAT  32
#define HID   128
#define OUTC  6

__device__ __forceinline__ float bf_lo(unsigned u) { return __uint_as_float(u << 16); }
__device__ __forceinline__ float bf_hi(unsigned u) { return __uint_as_float(u & 0xffff0000u); }
__device__ __forceinline__ unsigned short f2bf(float f) {
    unsigned x = __float_as_uint(f);
    return (unsigned short)((x + 0x7fffu + ((x >> 16) & 1u)) >> 16);   // RNE
}

// ---------------- conv1 (LDS-tiled): x [B,9,2048] -> relu -> pool2 -> h1 [B,16,1024] ---
__global__ __launch_bounds__(256) void k_conv1(const float* __restrict__ x,
                                               const float* __restrict__ w,
                                               const float* __restrict__ bias,
                                               float* __restrict__ h1) {
    __shared__ float sx[C_IN][264];
    __shared__ float swt[45 * 16];
    int b   = blockIdx.x >> 3;
    int qt  = blockIdx.x & 7;
    int tid = threadIdx.x;

    const float* xb = x + (size_t)b * C_IN * T0;
    int gbase = qt * 256 - 2;
    #pragma unroll
    for (int c = 0; c < C_IN; ++c)
        for (int i = tid; i < 260; i += 256) {
            int g = gbase + i;
            sx[c][i] = ((unsigned)g < T0) ? xb[c * T0 + g] : 0.f;
        }
    for (int idx = tid; idx < 720; idx += 256) {
        int o = idx & 15, ck = idx >> 4;
        swt[ck * 16 + o] = w[o * 45 + ck];
    }
    __syncthreads();

    int lane = tid & 63;
    int wv   = tid >> 6;
    int o    = lane & 15;
    int slot = lane >> 4;
    int ttl0 = wv * 32 + slot * 8;

    float acc[16];
    #pragma unroll
    for (int i = 0; i < 16; ++i) acc[i] = 0.f;

    #pragma unroll
    for (int c = 0; c < C_IN; ++c) {
        float wt[5];
        #pragma unroll
        for (int k = 0; k < 5; ++k) wt[k] = swt[(c * 5 + k) * 16 + o];
        #pragma unroll
        for (int cb = 0; cb < 2; ++cb) {
            int Pb = 2 * ttl0 + 8 * cb;
            float4 i0 = *(const float4*)&sx[c][Pb];
            float4 i1 = *(const float4*)&sx[c][Pb + 4];
            float4 i2 = *(const float4*)&sx[c][Pb + 8];
            float in[12] = {i0.x,i0.y,i0.z,i0.w, i1.x,i1.y,i1.z,i1.w, i2.x,i2.y,i2.z,i2.w};
            #pragma unroll
            for (int q = 0; q < 8; ++q) {
                float s = acc[cb * 8 + q];
                #pragma unroll
                for (int k = 0; k < 5; ++k) s += wt[k] * in[q + k];
                acc[cb * 8 + q] = s;
            }
        }
    }

    float bi = bias[o];
    float* hp = h1 + (size_t)(b * 16 + o) * T1 + qt * 128 + ttl0;
    #pragma unroll
    for (int cb = 0; cb < 2; ++cb) {
        float4 r;
        r.x = fmaxf(fmaxf(acc[cb*8+0], acc[cb*8+1]) + bi, 0.f);
        r.y = fmaxf(fmaxf(acc[cb*8+2], acc[cb*8+3]) + bi, 0.f);
        r.z = fmaxf(fmaxf(acc[cb*8+4], acc[cb*8+5]) + bi, 0.f);
        r.w = fmaxf(fmaxf(acc[cb*8+6], acc[cb*8+7]) + bi, 0.f);
        *(float4*)(hp + cb * 4) = r;
    }
}

// ---------------- conv2 (LDS-tiled): h1 -> relu -> pool2 -> nodes_s = nodes * dis[n] ----
__global__ __launch_bounds__(256) void k_conv2(const float* __restrict__ h1,
                                               const float* __restrict__ w,
                                               const float* __restrict__ bias,
                                               const float* __restrict__ dis,
                                               float* __restrict__ nodes_s) {
    __shared__ float sh[16][136];
    __shared__ float swt[80 * 32];
    int b   = blockIdx.x >> 3;
    int qt  = blockIdx.x & 7;
    int tid = threadIdx.x;

    const float* hb = h1 + (size_t)b * 16 * T1;
    int gbase = qt * 128 - 2;
    #pragma unroll
    for (int c = 0; c < 16; ++c)
        for (int i = tid; i < 132; i += 256) {
            int g = gbase + i;
            sh[c][i] = ((unsigned)g < T1) ? hb[c * T1 + g] : 0.f;
        }
    for (int idx = tid; idx < 2560; idx += 256) {
        int o = idx & 31, ck = idx >> 5;
        swt[ck * 32 + o] = w[o * 80 + ck];
    }
    __syncthreads();

    int lane = tid & 63;
    int wv   = tid >> 6;
    int o    = lane & 31;
    int slot = lane >> 5;
    int ttl0 = wv * 16 + slot * 8;

    float acc[16];
    #pragma unroll
    for (int i = 0; i < 16; ++i) acc[i] = 0.f;

    #pragma unroll
    for (int c = 0; c < 16; ++c) {
        float wt[5];
        #pragma unroll
        for (int k = 0; k < 5; ++k) wt[k] = swt[(c * 5 + k) * 32 + o];
        #pragma unroll
        for (int cb = 0; cb < 2; ++cb) {
            int Pb = 2 * ttl0 + 8 * cb;
            float4 i0 = *(const float4*)&sh[c][Pb];
            float4 i1 = *(const float4*)&sh[c][Pb + 4];
            float4 i2 = *(const float4*)&sh[c][Pb + 8];
            float in[12] = {i0.x,i0.y,i0.z,i0.w, i1.x,i1.y,i1.z,i1.w, i2.x,i2.y,i2.z,i2.w};
            #pragma unroll
            for (int q = 0; q < 8; ++q) {
                float s = acc[cb * 8 + q];
                #pragma unroll
                for (int k = 0; k < 5; ++k) s += wt[k] * in[q + k];
                acc[cb * 8 + q] = s;
            }
        }
    }

    float bi = bias[o];
    int node0 = b * T2 + qt * 64 + ttl0;
    size_t nbase = (size_t)node0 * FEAT + o;
    #pragma unroll
    for (int cb = 0; cb < 2; ++cb)
        #pragma unroll
        for (int jj = 0; jj < 4; ++jj) {
            float v = fmaxf(fmaxf(acc[cb*8+2*jj], acc[cb*8+2*jj+1]) + bi, 0.f);
            nodes_s[nbase + (size_t)(cb * 4 + jj) * FEAT] = v * dis[node0 + cb * 4 + jj];
        }
}

// ---------------- CSR build ----------------
__global__ __launch_bounds__(256) void k_deg(const int* __restrict__ ei,
                                             int* __restrict__ deg_i) {
    int e = blockIdx.x * 256 + threadIdx.x;
    if (e < EE) atomicAdd(&deg_i[ei[EE + e]], 1);
}

__global__ __launch_bounds__(256) void k_dis(const int* __restrict__ deg_i,
                                             float* __restrict__ dis) {
    int n = blockIdx.x * 256 + threadIdx.x;
    if (n < NN) dis[n] = rsqrtf((float)deg_i[n] + 1.0f);
}

__global__ __launch_bounds__(1024) void k_scan(const int* __restrict__ deg_i,
                                               int* __restrict__ cursor) {
    __shared__ int part[1024];
    int t = threadIdx.x;
    int base = t * 64;
    int s = 0;
    for (int i = 0; i < 64; ++i) s += deg_i[base + i];
    part[t] = s;
    __syncthreads();
    for (int off = 1; off < 1024; off <<= 1) {
        int v = 0;
        if (t >= off) v = part[t - off];
        __syncthreads();
        if (t >= off) part[t] += v;
        __syncthreads();
    }
    int run = (t == 0) ? 0 : part[t - 1];
    for (int i = 0; i < 64; ++i) {
        cursor[base + i] = run;
        run += deg_i[base + i];
    }
}

__global__ __launch_bounds__(256) void k_fill(const int* __restrict__ ei,
                                              int* __restrict__ cursor,
                                              int* __restrict__ csr_src) {
    int e = blockIdx.x * 256 + threadIdx.x;
    if (e >= EE) return;
    int s = ei[e];
    int d = ei[EE + e];
    int pos = atomicAdd(&cursor[d], 1);
    csr_src[pos] = s;
}

// ---------------- gather1 (32-dim, fp32): aggN[d] = dis[d]*(ns[d] + sum ns[src]) -------
__global__ __launch_bounds__(256) void k_gather1(const float* __restrict__ nodes_s,
                                                 const int* __restrict__ cursor,
                                                 const int* __restrict__ deg_i,
                                                 const int* __restrict__ csr_src,
                                                 const float* __restrict__ dis,
                                                 float* __restrict__ aggN) {
    int t = blockIdx.x * 256 + threadIdx.x;
    int node = t >> 3;                    // 8 lanes per node (float4 each)
    if (node >= NN) return;
    int lane = t & 7;
    int end = cursor[node];
    int beg = end - deg_i[node];
    const float4* xv = (const float4*)nodes_s;
    float4 acc = xv[(size_t)node * 8 + lane];       // self (already * dis[d])
    for (int j = beg; j < end; ++j) {
        int s = csr_src[j];
        float4 v = xv[(size_t)s * 8 + lane];
        acc.x += v.x; acc.y += v.y; acc.z += v.z; acc.w += v.w;
    }
    float dd = dis[node];
    float4 r; r.x = acc.x * dd; r.y = acc.y * dd; r.z = acc.z * dd; r.w = acc.w * dd;
    ((float4*)aggN)[(size_t)node * 8 + lane] = r;
}

// ---------------- gather2 (128-dim, bf16 in / fp32 out) --------------------------------
__global__ __launch_bounds__(256) void k_gather2(const unsigned short* __restrict__ xws2,
                                                 const int* __restrict__ cursor,
                                                 const int* __restrict__ deg_i,
                                                 const int* __restrict__ csr_src,
                                                 const float* __restrict__ dis,
                                                 float* __restrict__ agg) {
    int t = blockIdx.x * 256 + threadIdx.x;
    int node = t >> 4;                    // 16 lanes per node (8 bf16 each)
    if (node >= NN) return;
    int lane = t & 15;
    int end = cursor[node];
    int beg = end - deg_i[node];
    const uint4* xv = (const uint4*)xws2;      // row = 16 uint4
    uint4 q = xv[(size_t)node * 16 + lane];
    float a0 = bf_lo(q.x), a1 = bf_hi(q.x), a2 = bf_lo(q.y), a3 = bf_hi(q.y);
    float a4 = bf_lo(q.z), a5 = bf_hi(q.z), a6 = bf_lo(q.w), a7 = bf_hi(q.w);
    for (int j = beg; j < end; ++j) {
        int s = csr_src[j];
        uint4 p = xv[(size_t)s * 16 + lane];
        a0 += bf_lo(p.x); a1 += bf_hi(p.x); a2 += bf_lo(p.y); a3 += bf_hi(p.y);
        a4 += bf_lo(p.z); a5 += bf_hi(p.z); a6 += bf_lo(p.w); a7 += bf_hi(p.w);
    }
    float dd = dis[node];
    float* op = agg + (size_t)node * HID + lane * 8;
    float4 o0, o1;
    o0.x = a0 * dd; o0.y = a1 * dd; o0.z = a2 * dd; o0.w = a3 * dd;
    o1.x = a4 * dd; o1.y = a5 * dd; o1.z = a6 * dd; o1.w = a7 * dd;
    *(float4*)op       = o0;
    *(float4*)(op + 4) = o1;
}

// ---------------- register-tiled GEMM ----------------
// out[n][o] = (RELU_BIAS ? relu(A[n]+bias) : A[n]) @ W, optional *dis[n], fp32 or bf16 out
template<int K, bool RELU_BIAS, bool SCALE, bool BF16OUT>
__global__ __launch_bounds__(256) void k_gemm(const float* __restrict__ A,
                                              const float* __restrict__ W,     // [K][HID]
                                              const float* __restrict__ bias,
                                              const float* __restrict__ dis,
                                              void* __restrict__ outv) {
    constexpr int KC = 32;
    constexpr int CHUNKS = K / KC;
    __shared__ float sA[2][KC][128 + 4];
    __shared__ float sB[2][KC][128 + 4];
    int tid = threadIdx.x;
    int rowBase = blockIdx.x * 128;
    int tr = tid >> 4;
    int tc = tid & 15;

    float acc[8][8];
    #pragma unroll
    for (int i = 0; i < 8; ++i)
        #pragma unroll
        for (int j = 0; j < 8; ++j) acc[i][j] = 0.f;

    int ar = tid & 127;
    int aq = (tid >> 7) * 4;

    auto stage = [&](int cc, int bb) {
        const float* arow = A + (size_t)(rowBase + ar) * K + cc * KC + aq * 4;
        #pragma unroll
        for (int q = 0; q < 4; ++q) {
            float4 va = *(const float4*)(arow + q * 4);
            if (RELU_BIAS) {
                float4 vb = *(const float4*)(bias + cc * KC + (aq + q) * 4);
                va.x = fmaxf(va.x + vb.x, 0.f);
                va.y = fmaxf(va.y + vb.y, 0.f);
                va.z = fmaxf(va.z + vb.z, 0.f);
                va.w = fmaxf(va.w + vb.w, 0.f);
            }
            int kb = (aq + q) * 4;
            sA[bb][kb + 0][ar] = va.x;
            sA[bb][kb + 1][ar] = va.y;
            sA[bb][kb + 2][ar] = va.z;
            sA[bb][kb + 3][ar] = va.w;
        }
        #pragma unroll
        for (int it = 0; it < 4; ++it) {
            int i = tid + it * 256;
            int k  = i >> 5;
            int c4 = (i & 31) * 4;
            *(float4*)&sB[bb][k][c4] = *(const float4*)(W + (size_t)(cc * KC + k) * HID + c4);
        }
    };

    stage(0, 0);
    __syncthreads();
    for (int cc = 0; cc < CHUNKS; ++cc) {
        if (cc + 1 < CHUNKS) stage(cc + 1, (cc + 1) & 1);
        int bb = cc & 1;
        #pragma unroll 8
        for (int k = 0; k < KC; ++k) {
            float4 a0 = *(const float4*)&sA[bb][k][tr * 8];
            float4 a1 = *(const float4*)&sA[bb][k][tr * 8 + 4];
            float4 b0 = *(const float4*)&sB[bb][k][tc * 8];
            float4 b1 = *(const float4*)&sB[bb][k][tc * 8 + 4];
            float av[8] = {a0.x, a0.y, a0.z, a0.w, a1.x, a1.y, a1.z, a1.w};
            float bv[8] = {b0.x, b0.y, b0.z, b0.w, b1.x, b1.y, b1.z, b1.w};
            #pragma unroll
            for (int i = 0; i < 8; ++i)
                #pragma unroll
                for (int j = 0; j < 8; ++j) acc[i][j] += av[i] * bv[j];
        }
        __syncthreads();
    }

    #pragma unroll
    for (int i = 0; i < 8; ++i) {
        int row = rowBase + tr * 8 + i;
        float d = SCALE ? dis[row] : 1.0f;
        if (BF16OUT) {
            unsigned short us[8];
            #pragma unroll
            for (int j = 0; j < 8; ++j) us[j] = f2bf(acc[i][j] * d);
            uint4 pv;
            pv.x = (unsigned)us[0] | ((unsigned)us[1] << 16);
            pv.y = (unsigned)us[2] | ((unsigned)us[3] << 16);
            pv.z = (unsigned)us[4] | ((unsigned)us[5] << 16);
            pv.w = (unsigned)us[6] | ((unsigned)us[7] << 16);
            *(uint4*)((unsigned short*)outv + (size_t)row * HID + tc * 8) = pv;
        } else {
            float4 o0, o1;
            o0.x = acc[i][0] * d; o0.y = acc[i][1] * d; o0.z = acc[i][2] * d; o0.w = acc[i][3] * d;
            o1.x = acc[i][4] * d; o1.y = acc[i][5] * d; o1.z = acc[i][6] * d; o1.w = acc[i][7] * d;
            float* op = (float*)outv + (size_t)row * HID + tc * 8;
            *(float4*)op       = o0;
            *(float4*)(op + 4) = o1;
        }
    }
}

// ---------------- finalize ----------------
__global__ __launch_bounds__(128) void k_final(const float* __restrict__ agg2,
                                               const float* __restrict__ b2,
                                               const float* __restrict__ clsw,
                                               const float* __restrict__ clsb,
                                               float* __restrict__ out) {
    __shared__ float pooled[HID];
    int b = blockIdx.x;
    int f = threadIdx.x;
    float bo = b2[f];
    float sum = 0.f;
    const float* basep = agg2 + (size_t)b * T2 * HID + f;
    for (int tt = 0; tt < T2; ++tt)
        sum += fmaxf(basep[(size_t)tt * HID] + bo, 0.f);
    pooled[f] = sum * (1.0f / (float)T2);
    __syncthreads();
    if (f < OUTC) {
        float acc = clsb[f];
        #pragma unroll 8
        for (int k = 0; k < HID; ++k) acc += pooled[k] * clsw[k * OUTC + f];
        out[b * OUTC + f] = acc;
    }
}

extern "C" void kernel_launch(void* const* d_in, const int* in_sizes, int n_in,
                              void* d_out, int out_size, void* d_ws, size_t ws_size,
                              hipStream_t stream) {
    const float* x    = (const float*)d_in[0];
    const int*   ei   = (const int*)d_in[1];
    const float* c1w  = (const float*)d_in[2];
    const float* c1b  = (const float*)d_in[3];
    const float* c2w  = (const float*)d_in[4];
    const float* c2b  = (const float*)d_in[5];
    const float* g1w  = (const float*)d_in[6];
    const float* g1b  = (const float*)d_in[7];
    const float* g2w  = (const float*)d_in[8];
    const float* g2b  = (const float*)d_in[9];
    const float* clsw = (const float*)d_in[10];
    const float* clsb = (const float*)d_in[11];
    float* out = (float*)d_out;

    float* ws = (float*)d_ws;
    float* agg1     = ws;                        // [0, 8388608)  32 MB (agg2 overlays)
    float* agg2     = ws;
    float* h1       = ws + 8388608;              // 8 MB
    float* nodes_s  = ws + 10485760;             // 8 MB
    float* aggN     = ws + 12582912;             // 8 MB
    unsigned short* xws2 = (unsigned short*)(ws + 14680064);   // N*128 bf16 = 16 MB
    float* dis      = ws + 18874368;
    int* deg_i      = (int*)(ws + 18939904);
    int* cursor     = (int*)(ws + 19005440);
    int* csr_src    = (int*)(ws + 19070976);

    hipMemsetAsync(deg_i, 0, NN * sizeof(int), stream);

    // CSR build + normalization (before conv2: its store is pre-scaled by dis)
    k_deg <<<(EE + 255) / 256, 256, 0, stream>>>(ei, deg_i);
    k_scan<<<1, 1024, 0, stream>>>(deg_i, cursor);
    k_fill<<<(EE + 255) / 256, 256, 0, stream>>>(ei, cursor, csr_src);
    k_dis <<<(NN + 255) / 256, 256, 0, stream>>>(deg_i, dis);

    // temporal conv stack
    k_conv1<<<BB * 8, 256, 0, stream>>>(x, c1w, c1b, h1);
    k_conv2<<<BB * 8, 256, 0, stream>>>(h1, c2w, c2b, dis, nodes_s);

    // GCN layer 1: aggregate first (32-dim), then transform
    k_gather1<<<(NN * 8) / 256, 256, 0, stream>>>(nodes_s, cursor, deg_i, csr_src, dis, aggN);
    k_gemm<FEAT, false, false, false><<<NN / 128, 256, 0, stream>>>(aggN, g1w, nullptr, nullptr, agg1);

    // GCN layer 2: xws2 = (relu(agg1+b1) @ W2) * dis  (bf16), then aggregate
    k_gemm<HID, true, true, true><<<NN / 128, 256, 0, stream>>>(agg1, g2w, g1b, dis, xws2);
    k_gather2<<<(NN * 16) / 256, 256, 0, stream>>>(xws2, cursor, deg_i, csr_src, dis, agg2);

    // mean-pool + classifier
    k_final<<<BB, 128, 0, stream>>>(agg2, g2b, clsw, clsb, out);
}